// Round 1
// baseline (418.561 us; speedup 1.0000x reference)
//
#include <hip/hip_runtime.h>
#include <math.h>

#define BB 8
#define MM 2048
#define KK 64
#define CC 64
#define NTOT (BB*MM)
#define R2 0.04f
#define CAP 256

// ---------------------------------------------------------------- helpers
__device__ __forceinline__ unsigned long long shfl_xor_u64(unsigned long long x, int off) {
  int lo = __shfl_xor((int)(unsigned)(x & 0xFFFFFFFFull), off, 64);
  int hi = __shfl_xor((int)(unsigned)(x >> 32), off, 64);
  return (((unsigned long long)(unsigned)hi) << 32) | (unsigned)lo;
}

__device__ __forceinline__ unsigned long long wave_min_u64(unsigned long long x) {
#pragma unroll
  for (int off = 32; off; off >>= 1) {
    unsigned long long o = shfl_xor_u64(x, off);
    x = (o < x) ? o : x;
  }
  return x;
}

// ---------------------------------------------------------------- kernel 1: v/k/q projections
__global__ __launch_bounds__(256) void proj_kernel(
    const float* __restrict__ x,
    const float* __restrict__ w0, const float* __restrict__ b0,
    const float* __restrict__ w1, const float* __restrict__ b1,
    const float* __restrict__ w2, const float* __restrict__ b2,
    float* __restrict__ o0, float* __restrict__ o1, float* __restrict__ o2) {
  __shared__ float xs[64 * 64];
  __shared__ float wss[64 * 64];
  const int tid = threadIdx.x;
  const int r0 = blockIdx.x << 6;
  const float* w; const float* bv; float* o;
  if (blockIdx.y == 0)      { w = w0; bv = b0; o = o0; }
  else if (blockIdx.y == 1) { w = w1; bv = b1; o = o1; }
  else                      { w = w2; bv = b2; o = o2; }
  for (int i = tid; i < 4096; i += 256) {
    xs[i]  = x[(size_t)r0 * 64 + i];
    wss[i] = w[i];
  }
  __syncthreads();
  const int c = tid & 63, rg = tid >> 6;
  float acc[16];
#pragma unroll
  for (int r = 0; r < 16; ++r) acc[r] = 0.f;
  for (int k = 0; k < 64; ++k) {
    const float wvv = wss[(k << 6) + c];
#pragma unroll
    for (int r = 0; r < 16; ++r)
      acc[r] = fmaf(xs[((rg * 16 + r) << 6) + k], wvv, acc[r]);
  }
  const float bb = bv[c];
#pragma unroll
  for (int r = 0; r < 16; ++r)
    o[(size_t)(r0 + rg * 16 + r) * 64 + c] = acc[r] + bb;
}

// ---------------------------------------------------------------- kernel 2: exact radius-KNN (top-64, index tiebreak)
// output word: low 31 bits = cloud-local neighbor index j, bit 31 = valid (d2 <= R^2)
__global__ __launch_bounds__(256) void knn_kernel(const float* __restrict__ pos,
                                                  unsigned* __restrict__ nbr) {
  __shared__ float spos[MM * 3];
  __shared__ unsigned long long slist[4][CAP];
  const int bidx = blockIdx.x;
  const int b = bidx >> 9;        // 512 blocks per cloud (4 queries each)
  const int qblk = bidx & 511;
  const int tid = threadIdx.x;
  const float* pc = pos + (size_t)b * MM * 3;
  for (int i = tid; i < MM * 3; i += 256) spos[i] = pc[i];
  __syncthreads();
  const int wv = tid >> 6, lane = tid & 63;
  const int q = (qblk << 2) + wv;
  const float qx = spos[q * 3 + 0], qy = spos[q * 3 + 1], qz = spos[q * 3 + 2];
  unsigned bits[32];
  unsigned cnt = 0;
#pragma unroll
  for (int i = 0; i < 32; ++i) {
    const int j = lane + (i << 6);
    const float dx = qx - spos[j * 3 + 0];
    const float dy = qy - spos[j * 3 + 1];
    const float dz = qz - spos[j * 3 + 2];
    // match reference rounding exactly: ((dx*dx + dy*dy) + dz*dz), no fma contraction
    const float d2 = __fadd_rn(__fadd_rn(__fmul_rn(dx, dx), __fmul_rn(dy, dy)), __fmul_rn(dz, dz));
    const unsigned bt = __float_as_uint(d2);
    bits[i] = bt;
    const bool val = (d2 <= R2);
    const unsigned long long mb = __ballot(val);
    if (val) {
      const unsigned off = cnt + (unsigned)__popcll(mb & ((1ull << lane) - 1ull));
      if (off < CAP) slist[wv][off] = (((unsigned long long)bt) << 32) | (unsigned)j;
    }
    cnt += (unsigned)__popcll(mb);
  }
  __syncthreads();
  unsigned outv;
  if (cnt <= 64u) {
    // all within-radius points are in the top-64; out-of-radius slots are masked anyway
    if (lane < (int)cnt) outv = ((unsigned)slist[wv][lane]) | 0x80000000u;
    else                 outv = 0u;
  } else if (cnt <= (unsigned)CAP) {
    // exact top-64 among cnt (<=256) within-radius keys; each lane owns <=4 keys
    unsigned long long s0, s1, s2, s3, t;
    s0 = (lane       < (int)cnt) ? slist[wv][lane      ] : ~0ull;
    s1 = (lane + 64  < (int)cnt) ? slist[wv][lane + 64 ] : ~0ull;
    s2 = (lane + 128 < (int)cnt) ? slist[wv][lane + 128] : ~0ull;
    s3 = (lane + 192 < (int)cnt) ? slist[wv][lane + 192] : ~0ull;
    if (s1 < s0) { t = s0; s0 = s1; s1 = t; }
    if (s3 < s2) { t = s2; s2 = s3; s3 = t; }
    if (s2 < s0) { t = s0; s0 = s2; s2 = t; }
    if (s3 < s1) { t = s1; s1 = s3; s3 = t; }
    if (s2 < s1) { t = s1; s1 = s2; s2 = t; }
    unsigned long long my = 0;
    for (int it = 0; it < 64; ++it) {
      const unsigned long long gg = wave_min_u64(s0);
      if (lane == it) my = gg;
      if (s0 == gg) { s0 = s1; s1 = s2; s2 = s3; s3 = ~0ull; }
    }
    outv = ((unsigned)my) | 0x80000000u;  // all within radius
  } else {
    // (practically dead) exact fallback over all 2048 candidates
    unsigned long long cur = ~0ull;
#pragma unroll
    for (int i = 0; i < 32; ++i) {
      const unsigned long long k = (((unsigned long long)bits[i]) << 32) | (unsigned)(lane + (i << 6));
      cur = (k < cur) ? k : cur;
    }
    unsigned long long my = 0;
    for (int it = 0; it < 64; ++it) {
      const unsigned long long gg = wave_min_u64(cur);
      if (lane == it) my = gg;
      if (cur == gg) {
        cur = ~0ull;
#pragma unroll
        for (int i = 0; i < 32; ++i) {
          const unsigned long long k = (((unsigned long long)bits[i]) << 32) | (unsigned)(lane + (i << 6));
          if (k > gg && k < cur) cur = k;
        }
      }
    }
    const float d2s = __uint_as_float((unsigned)(my >> 32));
    outv = ((unsigned)my) | ((d2s <= R2) ? 0x80000000u : 0u);
  }
  nbr[((size_t)(b * MM + q)) * 64 + lane] = outv;
}

// ---------------------------------------------------------------- kernel 3: fused transformer conv
__global__ __launch_bounds__(256) void ptc_kernel(
    const float* __restrict__ pos, const float* __restrict__ nrm,
    const float* __restrict__ vv, const float* __restrict__ kf, const float* __restrict__ qq,
    const unsigned* __restrict__ nbr,
    const float* __restrict__ pos_w, const float* __restrict__ pos_b,
    const float* __restrict__ pos_g, const float* __restrict__ pos_bt,
    const float* __restrict__ attn_w, const float* __restrict__ attn_b,
    const float* __restrict__ attn_g, const float* __restrict__ attn_bt,
    float* __restrict__ out) {
  __shared__ float s_aw[4096];     // attn_w [d][c]
  __shared__ float s_t[4096];      // t[n][d] = q - k_j + delta
  __shared__ float s_de[4096];     // delta[n][c]
  __shared__ float s_rel[64 * 6];
  __shared__ float s_pw[6 * 64];
  __shared__ float s_red[4 * 64];
  __shared__ unsigned s_sel[64];
  const int qi = blockIdx.x;
  const int b = qi >> 11;
  const int tid = threadIdx.x;
  const int c = tid & 63, g4 = tid >> 6;
  const float bninv = 1.0f / sqrtf(1.0f + 1e-5f);
  for (int i = tid; i < 4096; i += 256) s_aw[i] = attn_w[i];
  for (int i = tid; i < 384; i += 256) s_pw[i] = pos_w[i];
  if (tid < 64) {
    const unsigned s = nbr[(size_t)qi * 64 + tid];
    s_sel[tid] = s;
    const int j = (int)(s & 0x7FFFFFFFu);
    const int jg = (b << 11) + j;
    s_rel[tid * 6 + 0] = pos[(size_t)qi * 3 + 0] - pos[(size_t)jg * 3 + 0];
    s_rel[tid * 6 + 1] = pos[(size_t)qi * 3 + 1] - pos[(size_t)jg * 3 + 1];
    s_rel[tid * 6 + 2] = pos[(size_t)qi * 3 + 2] - pos[(size_t)jg * 3 + 2];
    s_rel[tid * 6 + 3] = nrm[(size_t)qi * 3 + 0] - nrm[(size_t)jg * 3 + 0];
    s_rel[tid * 6 + 4] = nrm[(size_t)qi * 3 + 1] - nrm[(size_t)jg * 3 + 1];
    s_rel[tid * 6 + 5] = nrm[(size_t)qi * 3 + 2] - nrm[(size_t)jg * 3 + 2];
  }
  __syncthreads();
  // ---- delta + t build (each thread: column c for 16 neighbors)
  float pwc[6];
#pragma unroll
  for (int d = 0; d < 6; ++d) pwc[d] = s_pw[(d << 6) + c];
  const float pb = pos_b[c], pg = pos_g[c], pbt = pos_bt[c];
  const float qvc = qq[(size_t)qi * 64 + c];
#pragma unroll
  for (int i = 0; i < 16; ++i) {
    const int n = (g4 << 4) + i;
    float y = pb;
#pragma unroll
    for (int d = 0; d < 6; ++d) y += s_rel[n * 6 + d] * pwc[d];
    float de = pg * y * bninv + pbt;
    de = fmaxf(de, 0.f);
    s_de[(n << 6) + c] = de;
    const int j = (int)(s_sel[n] & 0x7FFFFFFFu);
    const float kv = kf[((size_t)((b << 11) + j) << 6) + c];
    s_t[(n << 6) + c] = qvc - kv + de;
  }
  __syncthreads();
  // ---- alpha = t @ attn_w  (bulk of FLOPs)
  float acc[16];
#pragma unroll
  for (int i = 0; i < 16; ++i) acc[i] = 0.f;
  for (int d = 0; d < 64; d += 4) {
    const float w0 = s_aw[((d + 0) << 6) + c];
    const float w1 = s_aw[((d + 1) << 6) + c];
    const float w2 = s_aw[((d + 2) << 6) + c];
    const float w3 = s_aw[((d + 3) << 6) + c];
#pragma unroll
    for (int i = 0; i < 16; ++i) {
      const int n = (g4 << 4) + i;
      const float4 tv = *(const float4*)&s_t[(n << 6) + d];
      acc[i] = fmaf(tv.x, w0, acc[i]);
      acc[i] = fmaf(tv.y, w1, acc[i]);
      acc[i] = fmaf(tv.z, w2, acc[i]);
      acc[i] = fmaf(tv.w, w3, acc[i]);
    }
  }
  // ---- bn + relu + mask, then per-channel softmax over the 64 neighbors
  const float ab = attn_b[c], ag = attn_g[c], abt = attn_bt[c];
  float a[16];
  float pm = -INFINITY;
#pragma unroll
  for (int i = 0; i < 16; ++i) {
    const int n = (g4 << 4) + i;
    float y = acc[i] + ab;
    float al = ag * y * bninv + abt;
    al = fmaxf(al, 0.f);
    const bool valid = (s_sel[n] >> 31) != 0u;
    a[i] = valid ? al : -INFINITY;
    pm = fmaxf(pm, a[i]);
  }
  s_red[(g4 << 6) + c] = pm;
  __syncthreads();
  const float m = fmaxf(fmaxf(s_red[c], s_red[64 + c]), fmaxf(s_red[128 + c], s_red[192 + c]));
  __syncthreads();
  float ps = 0.f;
#pragma unroll
  for (int i = 0; i < 16; ++i) {
    const float e = expf(a[i] - m);   // invalid -> exp(-inf) = 0
    a[i] = e;
    ps += e;
  }
  s_red[(g4 << 6) + c] = ps;
  __syncthreads();
  const float ssum = s_red[c] + s_red[64 + c] + s_red[128 + c] + s_red[192 + c];
  __syncthreads();
  // ---- out = sum_n w * (v_j + delta)
  const float rs = 1.0f / ssum;
  float o = 0.f;
#pragma unroll
  for (int i = 0; i < 16; ++i) {
    const int n = (g4 << 4) + i;
    const int j = (int)(s_sel[n] & 0x7FFFFFFFu);
    const float vj = vv[((size_t)((b << 11) + j) << 6) + c];
    o = fmaf(a[i] * rs, vj + s_de[(n << 6) + c], o);
  }
  s_red[(g4 << 6) + c] = o;
  __syncthreads();
  if (tid < 64)
    out[(size_t)qi * 64 + tid] = s_red[tid] + s_red[64 + tid] + s_red[128 + tid] + s_red[192 + tid];
}

// ---------------------------------------------------------------- launch
extern "C" void kernel_launch(void* const* d_in, const int* in_sizes, int n_in,
                              void* d_out, int out_size, void* d_ws, size_t ws_size,
                              hipStream_t stream) {
  const float* x      = (const float*)d_in[0];
  const float* pos    = (const float*)d_in[1];
  const float* nrm    = (const float*)d_in[2];
  // d_in[3] = batch (block-contiguous, unused)
  const float* lin_w  = (const float*)d_in[4];
  const float* lin_b  = (const float*)d_in[5];
  const float* lsw    = (const float*)d_in[6];
  const float* lsb    = (const float*)d_in[7];
  const float* ldw    = (const float*)d_in[8];
  const float* ldb    = (const float*)d_in[9];
  const float* pos_w  = (const float*)d_in[10];
  const float* pos_b  = (const float*)d_in[11];
  const float* pos_g  = (const float*)d_in[12];
  const float* pos_bt = (const float*)d_in[13];
  const float* attn_w = (const float*)d_in[14];
  const float* attn_b = (const float*)d_in[15];
  const float* attn_g = (const float*)d_in[16];
  const float* attn_bt= (const float*)d_in[17];
  float* out = (float*)d_out;

  float* wsf = (float*)d_ws;
  float* v   = wsf;
  float* kf  = wsf + (size_t)NTOT * 64;
  float* qv  = wsf + (size_t)2 * NTOT * 64;
  unsigned* nbr = (unsigned*)(wsf + (size_t)3 * NTOT * 64);

  proj_kernel<<<dim3(NTOT / 64, 3), 256, 0, stream>>>(
      x, lin_w, lin_b, lsw, lsb, ldw, ldb, v, kf, qv);
  knn_kernel<<<BB * (MM / 4), 256, 0, stream>>>(pos, nbr);
  ptc_kernel<<<NTOT, 256, 0, stream>>>(
      pos, nrm, v, kf, qv, nbr,
      pos_w, pos_b, pos_g, pos_bt,
      attn_w, attn_b, attn_g, attn_bt, out);
}

// Round 4
// 257.398 us; speedup vs baseline: 1.6261x; 1.6261x over previous
//
#include <hip/hip_runtime.h>
#include <math.h>

#define BB 8
#define MM 2048
#define KK 64
#define CC 64
#define NTOT (BB*MM)
#define R2 0.04f
#define CAP 256

typedef _Float16 h8 __attribute__((ext_vector_type(8)));
typedef float f32x4 __attribute__((ext_vector_type(4)));

// swizzled halfword index for a [64][64] f16 LDS tile (row stride 128B):
// 16B chunk index gets XORed with (row&7) to spread banks.
__device__ __forceinline__ int swz(int row, int col) {
  return (row << 6) + ((((col >> 3) ^ (row & 7)) << 3) | (col & 7));
}

// ---------------------------------------------------------------- helpers
__device__ __forceinline__ unsigned long long shfl_xor_u64(unsigned long long x, int off) {
  int lo = __shfl_xor((int)(unsigned)(x & 0xFFFFFFFFull), off, 64);
  int hi = __shfl_xor((int)(unsigned)(x >> 32), off, 64);
  return (((unsigned long long)(unsigned)hi) << 32) | (unsigned)lo;
}

__device__ __forceinline__ unsigned long long wave_min_u64(unsigned long long x) {
#pragma unroll
  for (int off = 32; off; off >>= 1) {
    unsigned long long o = shfl_xor_u64(x, off);
    x = (o < x) ? o : x;
  }
  return x;
}

// ---------------------------------------------------------------- kernel 0: attn_w^T hi/lo f16 split, pre-swizzled LDS image
__global__ __launch_bounds__(256) void prep_w(const float* __restrict__ attn_w,
                                              unsigned short* __restrict__ w_img) {
  const int idx = blockIdx.x * 256 + threadIdx.x;   // 16 blocks x 256 = 4096
  const int d = idx >> 6, cc = idx & 63;
  const float v = attn_w[idx];                      // attn_w[d][cc]
  const _Float16 h = (_Float16)v;
  const _Float16 l = (_Float16)(v - (float)h);
  const int pos = swz(cc, d);                       // transposed: row=cc, col=d
  w_img[pos] = __builtin_bit_cast(unsigned short, h);
  w_img[4096 + pos] = __builtin_bit_cast(unsigned short, l);
}

// ---------------------------------------------------------------- kernel 1: v/k/q projections
__global__ __launch_bounds__(256) void proj_kernel(
    const float* __restrict__ x,
    const float* __restrict__ w0, const float* __restrict__ b0,
    const float* __restrict__ w1, const float* __restrict__ b1,
    const float* __restrict__ w2, const float* __restrict__ b2,
    float* __restrict__ o0, float* __restrict__ o1, float* __restrict__ o2) {
  __shared__ float xs[64 * 64];
  __shared__ float wss[64 * 64];
  const int tid = threadIdx.x;
  const int r0 = blockIdx.x << 6;
  const float* w; const float* bv; float* o;
  if (blockIdx.y == 0)      { w = w0; bv = b0; o = o0; }
  else if (blockIdx.y == 1) { w = w1; bv = b1; o = o1; }
  else                      { w = w2; bv = b2; o = o2; }
  for (int i = tid; i < 4096; i += 256) {
    xs[i]  = x[(size_t)r0 * 64 + i];
    wss[i] = w[i];
  }
  __syncthreads();
  const int c = tid & 63, rg = tid >> 6;
  float acc[16];
#pragma unroll
  for (int r = 0; r < 16; ++r) acc[r] = 0.f;
  for (int k = 0; k < 64; ++k) {
    const float wvv = wss[(k << 6) + c];
#pragma unroll
    for (int r = 0; r < 16; ++r)
      acc[r] = fmaf(xs[((rg * 16 + r) << 6) + k], wvv, acc[r]);
  }
  const float bb = bv[c];
#pragma unroll
  for (int r = 0; r < 16; ++r)
    o[(size_t)(r0 + rg * 16 + r) * 64 + c] = acc[r] + bb;
}

// ---------------------------------------------------------------- kernel 2: exact radius-KNN (top-64, index tiebreak)
// output word: low 31 bits = cloud-local neighbor index j, bit 31 = valid (d2 <= R^2)
__global__ __launch_bounds__(256) void knn_kernel(const float* __restrict__ pos,
                                                  unsigned* __restrict__ nbr) {
  __shared__ float spos[MM * 3];
  __shared__ unsigned long long slist[4][CAP];
  const int bidx = blockIdx.x;
  const int b = bidx >> 9;        // 512 blocks per cloud (4 queries each)
  const int qblk = bidx & 511;
  const int tid = threadIdx.x;
  const float* pc = pos + (size_t)b * MM * 3;
  for (int i = tid; i < MM * 3; i += 256) spos[i] = pc[i];
  __syncthreads();
  const int wv = tid >> 6, lane = tid & 63;
  const int q = (qblk << 2) + wv;
  const float qx = spos[q * 3 + 0], qy = spos[q * 3 + 1], qz = spos[q * 3 + 2];
  unsigned bits[32];
  unsigned cnt = 0;
#pragma unroll
  for (int i = 0; i < 32; ++i) {
    const int j = lane + (i << 6);
    const float dx = qx - spos[j * 3 + 0];
    const float dy = qy - spos[j * 3 + 1];
    const float dz = qz - spos[j * 3 + 2];
    // match reference rounding exactly: ((dx*dx + dy*dy) + dz*dz), no fma contraction
    const float d2 = __fadd_rn(__fadd_rn(__fmul_rn(dx, dx), __fmul_rn(dy, dy)), __fmul_rn(dz, dz));
    const unsigned bt = __float_as_uint(d2);
    bits[i] = bt;
    const bool val = (d2 <= R2);
    const unsigned long long mb = __ballot(val);
    if (val) {
      const unsigned off = cnt + (unsigned)__popcll(mb & ((1ull << lane) - 1ull));
      if (off < CAP) slist[wv][off] = (((unsigned long long)bt) << 32) | (unsigned)j;
    }
    cnt += (unsigned)__popcll(mb);
  }
  __syncthreads();
  unsigned outv;
  if (cnt <= 64u) {
    if (lane < (int)cnt) outv = ((unsigned)slist[wv][lane]) | 0x80000000u;
    else                 outv = 0u;
  } else if (cnt <= (unsigned)CAP) {
    unsigned long long s0, s1, s2, s3, t;
    s0 = (lane       < (int)cnt) ? slist[wv][lane      ] : ~0ull;
    s1 = (lane + 64  < (int)cnt) ? slist[wv][lane + 64 ] : ~0ull;
    s2 = (lane + 128 < (int)cnt) ? slist[wv][lane + 128] : ~0ull;
    s3 = (lane + 192 < (int)cnt) ? slist[wv][lane + 192] : ~0ull;
    if (s1 < s0) { t = s0; s0 = s1; s1 = t; }
    if (s3 < s2) { t = s2; s2 = s3; s3 = t; }
    if (s2 < s0) { t = s0; s0 = s2; s2 = t; }
    if (s3 < s1) { t = s1; s1 = s3; s3 = t; }
    if (s2 < s1) { t = s1; s1 = s2; s2 = t; }
    unsigned long long my = 0;
    for (int it = 0; it < 64; ++it) {
      const unsigned long long gg = wave_min_u64(s0);
      if (lane == it) my = gg;
      if (s0 == gg) { s0 = s1; s1 = s2; s2 = s3; s3 = ~0ull; }
    }
    outv = ((unsigned)my) | 0x80000000u;
  } else {
    unsigned long long cur = ~0ull;
#pragma unroll
    for (int i = 0; i < 32; ++i) {
      const unsigned long long k = (((unsigned long long)bits[i]) << 32) | (unsigned)(lane + (i << 6));
      cur = (k < cur) ? k : cur;
    }
    unsigned long long my = 0;
    for (int it = 0; it < 64; ++it) {
      const unsigned long long gg = wave_min_u64(cur);
      if (lane == it) my = gg;
      if (cur == gg) {
        cur = ~0ull;
#pragma unroll
        for (int i = 0; i < 32; ++i) {
          const unsigned long long k = (((unsigned long long)bits[i]) << 32) | (unsigned)(lane + (i << 6));
          if (k > gg && k < cur) cur = k;
        }
      }
    }
    const float d2s = __uint_as_float((unsigned)(my >> 32));
    outv = ((unsigned)my) | ((d2s <= R2) ? 0x80000000u : 0u);
  }
  nbr[((size_t)(b * MM + q)) * 64 + lane] = outv;
}

// ---------------------------------------------------------------- kernel 3: fused transformer conv (MFMA fp16-split matmul)
__global__ __launch_bounds__(256) void ptc_kernel(
    const float* __restrict__ pos, const float* __restrict__ nrm,
    const float* __restrict__ vv, const float* __restrict__ kf, const float* __restrict__ qq,
    const unsigned* __restrict__ nbr, const unsigned short* __restrict__ w_img,
    const float* __restrict__ pos_w, const float* __restrict__ pos_b,
    const float* __restrict__ pos_g, const float* __restrict__ pos_bt,
    const float* __restrict__ attn_b,
    const float* __restrict__ attn_g, const float* __restrict__ attn_bt,
    float* __restrict__ out) {
  __shared__ __align__(16) unsigned short s_w[2 * 4096];   // wT hi | wT lo (swizzled)
  __shared__ __align__(16) unsigned short s_thi[4096];     // t hi (swizzled)
  __shared__ __align__(16) unsigned short s_tlo[4096];     // t lo (swizzled)
  __shared__ float s_de[64 * 65];                          // delta, padded stride
  __shared__ float s_rel[64 * 6];
  __shared__ unsigned s_sel[64];
  const int qi = blockIdx.x;
  const int b = qi >> 11;
  const int tid = threadIdx.x;
  const int c = tid & 63, g4 = tid >> 6;
  const float bninv = 1.0f / sqrtf(1.0f + 1e-5f);

  // stage attn_w image (layout already matches LDS)
  {
    const uint4* wi = (const uint4*)w_img;
    uint4* sw = (uint4*)s_w;
    for (int i = tid; i < 1024; i += 256) sw[i] = wi[i];
  }
  if (tid < 64) {
    const unsigned s = nbr[(size_t)qi * 64 + tid];
    s_sel[tid] = s;
    const int j = (int)(s & 0x7FFFFFFFu);
    const int jg = (b << 11) + j;
    s_rel[tid * 6 + 0] = pos[(size_t)qi * 3 + 0] - pos[(size_t)jg * 3 + 0];
    s_rel[tid * 6 + 1] = pos[(size_t)qi * 3 + 1] - pos[(size_t)jg * 3 + 1];
    s_rel[tid * 6 + 2] = pos[(size_t)qi * 3 + 2] - pos[(size_t)jg * 3 + 2];
    s_rel[tid * 6 + 3] = nrm[(size_t)qi * 3 + 0] - nrm[(size_t)jg * 3 + 0];
    s_rel[tid * 6 + 4] = nrm[(size_t)qi * 3 + 1] - nrm[(size_t)jg * 3 + 1];
    s_rel[tid * 6 + 5] = nrm[(size_t)qi * 3 + 2] - nrm[(size_t)jg * 3 + 2];
  }
  __syncthreads();

  // ---- delta + t build; split t into f16 hi/lo (thread: column c, 16 neighbors)
  {
    float pwc[6];
#pragma unroll
    for (int d = 0; d < 6; ++d) pwc[d] = pos_w[(d << 6) + c];
    const float pb = pos_b[c], pg = pos_g[c], pbt = pos_bt[c];
    const float qvc = qq[(size_t)qi * 64 + c];
    _Float16* thp = (_Float16*)s_thi;
    _Float16* tlp = (_Float16*)s_tlo;
#pragma unroll
    for (int i = 0; i < 16; ++i) {
      const int n = (g4 << 4) + i;
      float y = pb;
#pragma unroll
      for (int d = 0; d < 6; ++d) y += s_rel[n * 6 + d] * pwc[d];
      float de = fmaxf(pg * y * bninv + pbt, 0.f);
      s_de[n * 65 + c] = de;
      const int j = (int)(s_sel[n] & 0x7FFFFFFFu);
      const float kv = kf[((size_t)((b << 11) + j) << 6) + c];
      const float t = qvc - kv + de;
      const _Float16 th = (_Float16)t;
      const _Float16 tl = (_Float16)(t - (float)th);
      const int p = swz(n, c);
      thp[p] = th;
      tlp[p] = tl;
    }
  }
  __syncthreads();

  // ---- alpha = t @ attn_w via 3-term fp16-split MFMA; wave owns 16 output cols
  const int wv = tid >> 6;
  const int lane = tid & 63;
  const int lrow = lane >> 4, lcol = lane & 15;
  const int col = (wv << 4) + lcol;
  f32x4 acc[4];
#pragma unroll
  for (int mt = 0; mt < 4; ++mt) acc[mt] = (f32x4){0.f, 0.f, 0.f, 0.f};
#pragma unroll
  for (int ks = 0; ks < 2; ++ks) {
    const int kc = lrow + (ks << 2);   // 16B-chunk index of this lane's k-slice
    const h8 bh = *(const h8*)&s_w[(col << 6) + ((kc ^ (col & 7)) << 3)];
    const h8 bl = *(const h8*)&s_w[4096 + (col << 6) + ((kc ^ (col & 7)) << 3)];
#pragma unroll
    for (int mt = 0; mt < 4; ++mt) {
      const int m = (mt << 4) + lcol;
      const int off = (m << 6) + ((kc ^ (m & 7)) << 3);
      const h8 ah = *(const h8*)&s_thi[off];
      const h8 al = *(const h8*)&s_tlo[off];
      acc[mt] = __builtin_amdgcn_mfma_f32_16x16x32_f16(ah, bh, acc[mt], 0, 0, 0);
      acc[mt] = __builtin_amdgcn_mfma_f32_16x16x32_f16(al, bh, acc[mt], 0, 0, 0);
      acc[mt] = __builtin_amdgcn_mfma_f32_16x16x32_f16(ah, bl, acc[mt], 0, 0, 0);
    }
  }

  // ---- bn + relu + mask; per-column softmax over 64 neighbors (cross-lane 16/32)
  const float ab = attn_b[col], ag = attn_g[col], abt = attn_bt[col];
  float a[16];
  unsigned selv[16];
  float pm = -INFINITY;
#pragma unroll
  for (int mt = 0; mt < 4; ++mt) {
#pragma unroll
    for (int r = 0; r < 4; ++r) {
      const int n = (mt << 4) + (lrow << 2) + r;
      const unsigned s = s_sel[n];
      selv[mt * 4 + r] = s;
      const float al = fmaxf(ag * (acc[mt][r] + ab) * bninv + abt, 0.f);
      const float av = (s >> 31) ? al : -INFINITY;
      a[mt * 4 + r] = av;
      pm = fmaxf(pm, av);
    }
  }
  pm = fmaxf(pm, __shfl_xor(pm, 16, 64));
  pm = fmaxf(pm, __shfl_xor(pm, 32, 64));
  float ps = 0.f;
#pragma unroll
  for (int i = 0; i < 16; ++i) {
    const float e = expf(a[i] - pm);   // masked -> exp(-inf) = 0
    a[i] = e;
    ps += e;
  }
  ps += __shfl_xor(ps, 16, 64);
  ps += __shfl_xor(ps, 32, 64);
  const float rs = 1.0f / ps;

  // ---- out[col] = sum_n w_n * (v[j_n][col] + delta[n][col])
  float o = 0.f;
#pragma unroll
  for (int mt = 0; mt < 4; ++mt) {
#pragma unroll
    for (int r = 0; r < 4; ++r) {
      const int i = mt * 4 + r;
      const int n = (mt << 4) + (lrow << 2) + r;
      const int j = (int)(selv[i] & 0x7FFFFFFFu);
      const float vj = vv[(((size_t)((b << 11) + j)) << 6) + col];
      o = fmaf(a[i] * rs, vj + s_de[n * 65 + col], o);
    }
  }
  o += __shfl_xor(o, 16, 64);
  o += __shfl_xor(o, 32, 64);
  if (lrow == 0) out[(size_t)qi * 64 + col] = o;
}

// ---------------------------------------------------------------- launch
extern "C" void kernel_launch(void* const* d_in, const int* in_sizes, int n_in,
                              void* d_out, int out_size, void* d_ws, size_t ws_size,
                              hipStream_t stream) {
  const float* x      = (const float*)d_in[0];
  const float* pos    = (const float*)d_in[1];
  const float* nrm    = (const float*)d_in[2];
  const float* lin_w  = (const float*)d_in[4];
  const float* lin_b  = (const float*)d_in[5];
  const float* lsw    = (const float*)d_in[6];
  const float* lsb    = (const float*)d_in[7];
  const float* ldw    = (const float*)d_in[8];
  const float* ldb    = (const float*)d_in[9];
  const float* pos_w  = (const float*)d_in[10];
  const float* pos_b  = (const float*)d_in[11];
  const float* pos_g  = (const float*)d_in[12];
  const float* pos_bt = (const float*)d_in[13];
  const float* attn_w = (const float*)d_in[14];
  const float* attn_b = (const float*)d_in[15];
  const float* attn_g = (const float*)d_in[16];
  const float* attn_bt= (const float*)d_in[17];
  float* out = (float*)d_out;

  float* wsf = (float*)d_ws;
  float* v   = wsf;
  float* kf  = wsf + (size_t)NTOT * 64;
  float* qv  = wsf + (size_t)2 * NTOT * 64;
  unsigned* nbr = (unsigned*)(wsf + (size_t)3 * NTOT * 64);
  unsigned short* w_img = (unsigned short*)(wsf + (size_t)4 * NTOT * 64);

  prep_w<<<16, 256, 0, stream>>>(attn_w, w_img);
  proj_kernel<<<dim3(NTOT / 64, 3), 256, 0, stream>>>(
      x, lin_w, lin_b, lsw, lsb, ldw, ldb, v, kf, qv);
  knn_kernel<<<BB * (MM / 4), 256, 0, stream>>>(pos, nbr);
  ptc_kernel<<<NTOT, 256, 0, stream>>>(
      pos, nrm, v, kf, qv, nbr, w_img,
      pos_w, pos_b, pos_g, pos_bt,
      attn_b, attn_g, attn_bt, out);
}

// Round 5
// 135.548 us; speedup vs baseline: 3.0879x; 1.8989x over previous
//
#include <hip/hip_runtime.h>
#include <math.h>

#define BB 8
#define MM 2048
#define KK 64
#define CC 64
#define NTOT (BB*MM)
#define R2 0.04f
#define CAP 256

typedef _Float16 h8 __attribute__((ext_vector_type(8)));
typedef _Float16 h4 __attribute__((ext_vector_type(4)));
typedef float f32x4 __attribute__((ext_vector_type(4)));

// swizzled halfword index for a [64][64] f16 LDS tile (row stride 128B):
// 16B chunk index gets XORed with (row&7) to spread banks.
__device__ __forceinline__ int swz(int row, int col) {
  return (row << 6) + ((((col >> 3) ^ (row & 7)) << 3) | (col & 7));
}

// ---------------------------------------------------------------- helpers
__device__ __forceinline__ unsigned long long shfl_xor_u64(unsigned long long x, int off) {
  int lo = __shfl_xor((int)(unsigned)(x & 0xFFFFFFFFull), off, 64);
  int hi = __shfl_xor((int)(unsigned)(x >> 32), off, 64);
  return (((unsigned long long)(unsigned)hi) << 32) | (unsigned)lo;
}

__device__ __forceinline__ unsigned long long wave_min_u64(unsigned long long x) {
#pragma unroll
  for (int off = 32; off; off >>= 1) {
    unsigned long long o = shfl_xor_u64(x, off);
    x = (o < x) ? o : x;
  }
  return x;
}

__device__ __forceinline__ unsigned long long wave_max_u64(unsigned long long x) {
#pragma unroll
  for (int off = 32; off; off >>= 1) {
    unsigned long long o = shfl_xor_u64(x, off);
    x = (o > x) ? o : x;
  }
  return x;
}

// ---------------------------------------------------------------- kernel 0: weight images (f16)
// w_img: attn_w^T hi, swizzled [64 outcol][64 k] (4096 hw)
// pw_img: pos_w as [64 col][24 k-padded] f16, k>=6 zero (1536 hw)
__global__ __launch_bounds__(256) void prep_w(const float* __restrict__ attn_w,
                                              const float* __restrict__ pos_w,
                                              unsigned short* __restrict__ w_img,
                                              unsigned short* __restrict__ pw_img) {
  const int idx = blockIdx.x * 256 + threadIdx.x;   // 16 blocks x 256 = 4096
  if (idx < 4096) {
    const int d = idx >> 6, cc = idx & 63;
    const float v = attn_w[idx];                    // attn_w[d][cc]
    w_img[swz(cc, d)] = __builtin_bit_cast(unsigned short, (_Float16)v);
  }
  if (idx < 64 * 24) {
    const int col = idx / 24, k = idx - col * 24;
    const float v = (k < 6) ? pos_w[k * 64 + col] : 0.f;
    pw_img[idx] = __builtin_bit_cast(unsigned short, (_Float16)v);
  }
}

// ---------------------------------------------------------------- kernel 1: v/k/q projections
__global__ __launch_bounds__(256) void proj_kernel(
    const float* __restrict__ x,
    const float* __restrict__ w0, const float* __restrict__ b0,
    const float* __restrict__ w1, const float* __restrict__ b1,
    const float* __restrict__ w2, const float* __restrict__ b2,
    float* __restrict__ o0, float* __restrict__ o1, float* __restrict__ o2) {
  __shared__ float xs[64 * 64];
  __shared__ float wss[64 * 64];
  const int tid = threadIdx.x;
  const int r0 = blockIdx.x << 6;
  const float* w; const float* bv; float* o;
  if (blockIdx.y == 0)      { w = w0; bv = b0; o = o0; }
  else if (blockIdx.y == 1) { w = w1; bv = b1; o = o1; }
  else                      { w = w2; bv = b2; o = o2; }
  for (int i = tid; i < 4096; i += 256) {
    xs[i]  = x[(size_t)r0 * 64 + i];
    wss[i] = w[i];
  }
  __syncthreads();
  const int c = tid & 63, rg = tid >> 6;
  float acc[16];
#pragma unroll
  for (int r = 0; r < 16; ++r) acc[r] = 0.f;
  for (int k = 0; k < 64; ++k) {
    const float wvv = wss[(k << 6) + c];
#pragma unroll
    for (int r = 0; r < 16; ++r)
      acc[r] = fmaf(xs[((rg * 16 + r) << 6) + k], wvv, acc[r]);
  }
  const float bb = bv[c];
#pragma unroll
  for (int r = 0; r < 16; ++r)
    o[(size_t)(r0 + rg * 16 + r) * 64 + c] = acc[r] + bb;
}

// ---------------------------------------------------------------- kernel 2: exact radius-KNN (top-64 SET, index tiebreak)
// output word: low 31 bits = cloud-local neighbor index j, bit 31 = valid (d2 <= R^2)
__global__ __launch_bounds__(256) void knn_kernel(const float* __restrict__ pos,
                                                  unsigned* __restrict__ nbr) {
  __shared__ float spos[MM * 3];
  __shared__ unsigned long long slist[4][CAP];
  const int bidx = blockIdx.x;
  const int b = bidx >> 9;        // 512 blocks per cloud (4 queries each)
  const int qblk = bidx & 511;
  const int tid = threadIdx.x;
  const float* pc = pos + (size_t)b * MM * 3;
  for (int i = tid; i < MM * 3; i += 256) spos[i] = pc[i];
  __syncthreads();
  const int wv = tid >> 6, lane = tid & 63;
  const int q = (qblk << 2) + wv;
  const float qx = spos[q * 3 + 0], qy = spos[q * 3 + 1], qz = spos[q * 3 + 2];
  unsigned bits[32];
  unsigned cnt = 0;
#pragma unroll
  for (int i = 0; i < 32; ++i) {
    const int j = lane + (i << 6);
    const float dx = qx - spos[j * 3 + 0];
    const float dy = qy - spos[j * 3 + 1];
    const float dz = qz - spos[j * 3 + 2];
    // match reference rounding exactly: ((dx*dx + dy*dy) + dz*dz), no fma contraction
    const float d2 = __fadd_rn(__fadd_rn(__fmul_rn(dx, dx), __fmul_rn(dy, dy)), __fmul_rn(dz, dz));
    const unsigned bt = __float_as_uint(d2);
    bits[i] = bt;
    const bool val = (d2 <= R2);
    const unsigned long long mb = __ballot(val);
    if (val) {
      const unsigned off = cnt + (unsigned)__popcll(mb & ((1ull << lane) - 1ull));
      if (off < CAP) slist[wv][off] = (((unsigned long long)bt) << 32) | (unsigned)j;
    }
    cnt += (unsigned)__popcll(mb);
  }
  __syncthreads();
  unsigned outv;
  if (cnt <= 64u) {
    // all within-radius points are in the top-64 (set semantics; order irrelevant)
    if (lane < (int)cnt) outv = ((unsigned)slist[wv][lane]) | 0x80000000u;
    else                 outv = 0u;
  } else if (cnt <= (unsigned)CAP) {
    // exact top-64 SET among cnt (<=256) within-radius keys; each lane owns <=4 sorted keys
    unsigned long long s0, s1, s2, s3, t;
    s0 = (lane       < (int)cnt) ? slist[wv][lane      ] : ~0ull;
    s1 = (lane + 64  < (int)cnt) ? slist[wv][lane + 64 ] : ~0ull;
    s2 = (lane + 128 < (int)cnt) ? slist[wv][lane + 128] : ~0ull;
    s3 = (lane + 192 < (int)cnt) ? slist[wv][lane + 192] : ~0ull;
    if (s1 < s0) { t = s0; s0 = s1; s1 = t; }
    if (s3 < s2) { t = s2; s2 = s3; s3 = t; }
    if (s2 < s0) { t = s0; s0 = s2; s2 = t; }
    if (s3 < s1) { t = s1; s1 = s3; s3 = t; }
    if (s2 < s1) { t = s1; s1 = s2; s2 = t; }
    if (cnt <= 128u) {
      // pop the (cnt-64) LARGEST; the 64 remaining are the answer set.
      const int pops = (int)cnt - 64;
      int rl = (cnt > (unsigned)lane) ? (int)((cnt - (unsigned)lane + 63u) >> 6) : 0;
      if (rl > 4) rl = 4;
      int ti = rl - 1;                     // top index of remaining reals
      for (int p = 0; p < pops; ++p) {     // pops is wave-uniform
        const unsigned long long mx =
            (ti == 3) ? s3 : (ti == 2) ? s2 : (ti == 1) ? s1 : (ti == 0) ? s0 : 0ull;
        const unsigned long long g = wave_max_u64(mx);
        if (ti >= 0 && mx == g) ti--;      // keys unique -> exactly one lane pops
      }
      const int c = ti + 1;                // survivors in this lane (sum over lanes = 64)
      const unsigned long long b0 = __ballot(c & 1);
      const unsigned long long b1 = __ballot(c & 2);
      const unsigned long long b2 = __ballot(c & 4);
      const unsigned long long lm = (1ull << lane) - 1ull;
      const int pre = __popcll(b0 & lm) + 2 * __popcll(b1 & lm) + 4 * __popcll(b2 & lm);
      if (c > 0) slist[wv][pre + 0] = s0;
      if (c > 1) slist[wv][pre + 1] = s1;
      if (c > 2) slist[wv][pre + 2] = s2;
      if (c > 3) slist[wv][pre + 3] = s3;
      __asm volatile("s_waitcnt lgkmcnt(0)" ::: "memory");
      outv = ((unsigned)slist[wv][lane]) | 0x80000000u;
    } else {
      // pop 64 smallest (old path)
      unsigned long long my = 0;
      for (int it = 0; it < 64; ++it) {
        const unsigned long long gg = wave_min_u64(s0);
        if (lane == it) my = gg;
        if (s0 == gg) { s0 = s1; s1 = s2; s2 = s3; s3 = ~0ull; }
      }
      outv = ((unsigned)my) | 0x80000000u;
    }
  } else {
    // (practically dead) exact fallback over all 2048 candidates
    unsigned long long cur = ~0ull;
#pragma unroll
    for (int i = 0; i < 32; ++i) {
      const unsigned long long k = (((unsigned long long)bits[i]) << 32) | (unsigned)(lane + (i << 6));
      cur = (k < cur) ? k : cur;
    }
    unsigned long long my = 0;
    for (int it = 0; it < 64; ++it) {
      const unsigned long long gg = wave_min_u64(cur);
      if (lane == it) my = gg;
      if (cur == gg) {
        cur = ~0ull;
#pragma unroll
        for (int i = 0; i < 32; ++i) {
          const unsigned long long k = (((unsigned long long)bits[i]) << 32) | (unsigned)(lane + (i << 6));
          if (k > gg && k < cur) cur = k;
        }
      }
    }
    const float d2s = __uint_as_float((unsigned)(my >> 32));
    outv = ((unsigned)my) | ((d2s <= R2) ? 0x80000000u : 0u);
  }
  nbr[((size_t)(b * MM + q)) * 64 + lane] = outv;
}

// ---------------------------------------------------------------- kernel 3: fused transformer conv
// one query per block; thread owns channel col = wv*16 + (lane&15), rows n = 16mt+4*(lane>>4)+r
__global__ __launch_bounds__(256, 4) void ptc_kernel(
    const float* __restrict__ pos, const float* __restrict__ nrm,
    const float* __restrict__ vv, const float* __restrict__ kf, const float* __restrict__ qq,
    const unsigned* __restrict__ nbr,
    const unsigned short* __restrict__ w_img, const unsigned short* __restrict__ pw_img,
    const float* __restrict__ pos_b, const float* __restrict__ pos_g, const float* __restrict__ pos_bt,
    const float* __restrict__ attn_b, const float* __restrict__ attn_g, const float* __restrict__ attn_bt,
    float* __restrict__ out) {
  __shared__ __align__(16) unsigned short s_w[4096];      // 8KB swizzled wT (hi)
  __shared__ __align__(16) unsigned short s_thi[4096];    // 8KB swizzled t (f16)
  __shared__ __align__(16) unsigned short s_pw[64 * 24];  // 3KB [col][k24]
  __shared__ __align__(16) unsigned short s_relh[64 * 24];// 3KB [n][k24], k<6 = rel, 6..15 = 0
  __shared__ unsigned s_sel[64];
  const int qi = blockIdx.x;
  const int b = qi >> 11;
  const int tid = threadIdx.x;
  const int wv = tid >> 6, lane = tid & 63;
  const int lrow = lane >> 4, lcol = lane & 15;
  const int col = (wv << 4) + lcol;
  const float bninv = 1.0f / sqrtf(1.0f + 1e-5f);

  // ---- stage weight images
  {
    const uint4* wi = (const uint4*)w_img;
    uint4* sw = (uint4*)s_w;
#pragma unroll
    for (int i = 0; i < 2; ++i) sw[tid + 256 * i] = wi[tid + 256 * i];
    if (tid < 192) ((uint4*)s_pw)[tid] = ((const uint4*)pw_img)[tid];
  }
  // ---- neighbor ids + rel rows (f16, zero-padded to k=16)
  if (tid < 64) {
    const unsigned s = nbr[(size_t)qi * 64 + tid];
    s_sel[tid] = s;
    const int j = (int)(s & 0x7FFFFFFFu);
    const int jg = (b << 11) + j;
    h8 hv;
    hv[0] = (_Float16)(pos[(size_t)qi * 3 + 0] - pos[(size_t)jg * 3 + 0]);
    hv[1] = (_Float16)(pos[(size_t)qi * 3 + 1] - pos[(size_t)jg * 3 + 1]);
    hv[2] = (_Float16)(pos[(size_t)qi * 3 + 2] - pos[(size_t)jg * 3 + 2]);
    hv[3] = (_Float16)(nrm[(size_t)qi * 3 + 0] - nrm[(size_t)jg * 3 + 0]);
    hv[4] = (_Float16)(nrm[(size_t)qi * 3 + 1] - nrm[(size_t)jg * 3 + 1]);
    hv[5] = (_Float16)(nrm[(size_t)qi * 3 + 2] - nrm[(size_t)jg * 3 + 2]);
    hv[6] = (_Float16)0.f; hv[7] = (_Float16)0.f;
    *(h8*)&s_relh[tid * 24] = hv;
    h8 zz = (h8)(_Float16)0.f;
    *(h8*)&s_relh[tid * 24 + 8] = zz;
  }
  __syncthreads();

  // ---- delta-pre = rel @ pos_w via 4 MFMAs (K padded to 16, zero w rows)
  f32x4 dacc[4];
  {
    const h4 bpw = *(const h4*)&s_pw[col * 24 + (lrow << 2)];
#pragma unroll
    for (int mt = 0; mt < 4; ++mt) {
      const h4 ar = *(const h4*)&s_relh[((mt << 4) + lcol) * 24 + (lrow << 2)];
      dacc[mt] = __builtin_amdgcn_mfma_f32_16x16x16f16(ar, bpw, (f32x4){0.f, 0.f, 0.f, 0.f}, 0, 0, 0);
    }
  }

  // ---- elementwise: delta (kept in regs), t = q - k + delta -> f16 LDS
  float def[16];
  unsigned selv[16];
  {
    const float pb = pos_b[col], pg = pos_g[col], pbt = pos_bt[col];
    const float qvc = qq[(size_t)qi * 64 + col];
#pragma unroll
    for (int mt = 0; mt < 4; ++mt) {
#pragma unroll
      for (int r = 0; r < 4; ++r) {
        const int i = (mt << 2) + r;
        const int n = (mt << 4) + (lrow << 2) + r;
        const float de = fmaxf(pg * (dacc[mt][r] + pb) * bninv + pbt, 0.f);
        def[i] = de;
        const unsigned s = s_sel[n];
        selv[i] = s;
        const int j = (int)(s & 0x7FFFFFFFu);
        const float kv = kf[(((size_t)((b << 11) + j)) << 6) + col];
        const float t = qvc - kv + de;
        s_thi[swz(n, col)] = __builtin_bit_cast(unsigned short, (_Float16)t);
      }
    }
  }
  __syncthreads();

  // ---- alpha = t @ attn_w (f16 MFMA, wave owns 16 output cols)
  f32x4 acc[4];
#pragma unroll
  for (int mt = 0; mt < 4; ++mt) acc[mt] = (f32x4){0.f, 0.f, 0.f, 0.f};
#pragma unroll
  for (int ks = 0; ks < 2; ++ks) {
    const int kc = lrow + (ks << 2);
    const h8 bh = *(const h8*)&s_w[(col << 6) + ((kc ^ (col & 7)) << 3)];
#pragma unroll
    for (int mt = 0; mt < 4; ++mt) {
      const int m = (mt << 4) + lcol;
      const h8 ah = *(const h8*)&s_thi[(m << 6) + ((kc ^ (m & 7)) << 3)];
      acc[mt] = __builtin_amdgcn_mfma_f32_16x16x32_f16(ah, bh, acc[mt], 0, 0, 0);
    }
  }

  // ---- bn + relu + mask; per-channel softmax over 64 neighbors (shfl 16/32)
  const float ab = attn_b[col], ag = attn_g[col], abt = attn_bt[col];
  float a[16];
  float pm = -INFINITY;
#pragma unroll
  for (int mt = 0; mt < 4; ++mt) {
#pragma unroll
    for (int r = 0; r < 4; ++r) {
      const int i = (mt << 2) + r;
      const float al = fmaxf(ag * (acc[mt][r] + ab) * bninv + abt, 0.f);
      const float av = (selv[i] >> 31) ? al : -INFINITY;
      a[i] = av;
      pm = fmaxf(pm, av);
    }
  }
  pm = fmaxf(pm, __shfl_xor(pm, 16, 64));
  pm = fmaxf(pm, __shfl_xor(pm, 32, 64));
  float ps = 0.f;
#pragma unroll
  for (int i = 0; i < 16; ++i) {
    const float e = __expf(a[i] - pm);   // masked -> exp(-inf) = 0
    a[i] = e;
    ps += e;
  }
  ps += __shfl_xor(ps, 16, 64);
  ps += __shfl_xor(ps, 32, 64);

  // ---- out[col] = (sum_n e_n * (v[j_n][col] + delta[n][col])) / sum_n e_n
  float o = 0.f;
#pragma unroll
  for (int i = 0; i < 16; ++i) {
    const int j = (int)(selv[i] & 0x7FFFFFFFu);
    const float vj = vv[(((size_t)((b << 11) + j)) << 6) + col];
    o = fmaf(a[i], vj + def[i], o);
  }
  o += __shfl_xor(o, 16, 64);
  o += __shfl_xor(o, 32, 64);
  if (lrow == 0) out[(size_t)qi * 64 + col] = o * (1.0f / ps);
}

// ---------------------------------------------------------------- launch
extern "C" void kernel_launch(void* const* d_in, const int* in_sizes, int n_in,
                              void* d_out, int out_size, void* d_ws, size_t ws_size,
                              hipStream_t stream) {
  const float* x      = (const float*)d_in[0];
  const float* pos    = (const float*)d_in[1];
  const float* nrm    = (const float*)d_in[2];
  const float* lin_w  = (const float*)d_in[4];
  const float* lin_b  = (const float*)d_in[5];
  const float* lsw    = (const float*)d_in[6];
  const float* lsb    = (const float*)d_in[7];
  const float* ldw    = (const float*)d_in[8];
  const float* ldb    = (const float*)d_in[9];
  const float* pos_w  = (const float*)d_in[10];
  const float* pos_b  = (const float*)d_in[11];
  const float* pos_g  = (const float*)d_in[12];
  const float* pos_bt = (const float*)d_in[13];
  const float* attn_w = (const float*)d_in[14];
  const float* attn_b = (const float*)d_in[15];
  const float* attn_g = (const float*)d_in[16];
  const float* attn_bt= (const float*)d_in[17];
  float* out = (float*)d_out;

  float* wsf = (float*)d_ws;
  float* v   = wsf;
  float* kf  = wsf + (size_t)NTOT * 64;
  float* qv  = wsf + (size_t)2 * NTOT * 64;
  unsigned* nbr = (unsigned*)(wsf + (size_t)3 * NTOT * 64);
  unsigned short* w_img  = (unsigned short*)(wsf + (size_t)4 * NTOT * 64);
  unsigned short* pw_img = w_img + 4096;

  prep_w<<<16, 256, 0, stream>>>(attn_w, pos_w, w_img, pw_img);
  proj_kernel<<<dim3(NTOT / 64, 3), 256, 0, stream>>>(
      x, lin_w, lin_b, lsw, lsb, ldw, ldb, v, kf, qv);
  knn_kernel<<<BB * (MM / 4), 256, 0, stream>>>(pos, nbr);
  ptc_kernel<<<NTOT, 256, 0, stream>>>(
      pos, nrm, v, kf, qv, nbr, w_img, pw_img,
      pos_b, pos_g, pos_bt,
      attn_b, attn_g, attn_bt, out);
}

// Round 7
// 131.408 us; speedup vs baseline: 3.1852x; 1.0315x over previous
//
#include <hip/hip_runtime.h>
#include <math.h>

#define BB 8
#define MM 2048
#define KK 64
#define CC 64
#define NTOT (BB*MM)
#define R2 0.04f
#define CAP 256

typedef _Float16 h8 __attribute__((ext_vector_type(8)));
typedef _Float16 h4 __attribute__((ext_vector_type(4)));
typedef float f32x4 __attribute__((ext_vector_type(4)));

// swizzled halfword index for a [64][64] f16 LDS tile (row stride 128B):
// 16B chunk index gets XORed with (row&7) to spread banks.
__device__ __forceinline__ int swz(int row, int col) {
  return (row << 6) + ((((col >> 3) ^ (row & 7)) << 3) | (col & 7));
}

// ---------------------------------------------------------------- helpers
__device__ __forceinline__ unsigned long long shfl_xor_u64(unsigned long long x, int off) {
  int lo = __shfl_xor((int)(unsigned)(x & 0xFFFFFFFFull), off, 64);
  int hi = __shfl_xor((int)(unsigned)(x >> 32), off, 64);
  return (((unsigned long long)(unsigned)hi) << 32) | (unsigned)lo;
}

__device__ __forceinline__ unsigned long long wave_min_u64(unsigned long long x) {
#pragma unroll
  for (int off = 32; off; off >>= 1) {
    unsigned long long o = shfl_xor_u64(x, off);
    x = (o < x) ? o : x;
  }
  return x;
}

__device__ __forceinline__ unsigned long long wave_max_u64(unsigned long long x) {
#pragma unroll
  for (int off = 32; off; off >>= 1) {
    unsigned long long o = shfl_xor_u64(x, off);
    x = (o > x) ? o : x;
  }
  return x;
}

// ---------------------------------------------------------------- kernel 0: weight images + folded BN constants
// w_img  : attn_w^T f16, swizzled [64 outcol][64 k]          (4096 hw)
// pw_img : pos_w as [64 col][24 k-padded] f16, k>=6 zero     (1536 hw)
// pj_img : 3 proj weights^T, hi/lo f16 swizzled, o*8192+{0,4096} (24576 hw)
// bnc    : [pA|pB|aA|aB] 4x64 f32
__global__ __launch_bounds__(256) void prep_w(
    const float* __restrict__ attn_w, const float* __restrict__ pos_w,
    const float* __restrict__ lin_w, const float* __restrict__ lsw, const float* __restrict__ ldw,
    const float* __restrict__ pos_b, const float* __restrict__ pos_g, const float* __restrict__ pos_bt,
    const float* __restrict__ attn_b, const float* __restrict__ attn_g, const float* __restrict__ attn_bt,
    unsigned short* __restrict__ w_img, unsigned short* __restrict__ pw_img,
    unsigned short* __restrict__ pj_img, float* __restrict__ bnc) {
  const int idx = blockIdx.x * 256 + threadIdx.x;   // 16 blocks x 256 = 4096
  const float bninv = 1.0f / sqrtf(1.0f + 1e-5f);
  if (idx < 4096) {
    const int d = idx >> 6, cc = idx & 63;
    const int sp = swz(cc, d);                      // transposed: row=outcol, col=k
    w_img[sp] = __builtin_bit_cast(unsigned short, (_Float16)attn_w[idx]);
    const float v0 = lin_w[idx];
    const _Float16 h0 = (_Float16)v0;
    pj_img[sp] = __builtin_bit_cast(unsigned short, h0);
    pj_img[4096 + sp] = __builtin_bit_cast(unsigned short, (_Float16)(v0 - (float)h0));
    const float v1 = lsw[idx];
    const _Float16 h1 = (_Float16)v1;
    pj_img[8192 + sp] = __builtin_bit_cast(unsigned short, h1);
    pj_img[12288 + sp] = __builtin_bit_cast(unsigned short, (_Float16)(v1 - (float)h1));
    const float v2 = ldw[idx];
    const _Float16 h2 = (_Float16)v2;
    pj_img[16384 + sp] = __builtin_bit_cast(unsigned short, h2);
    pj_img[20480 + sp] = __builtin_bit_cast(unsigned short, (_Float16)(v2 - (float)h2));
  }
  if (idx < 64 * 24) {
    const int col = idx / 24, k = idx - col * 24;
    const float v = (k < 6) ? pos_w[k * 64 + col] : 0.f;
    pw_img[idx] = __builtin_bit_cast(unsigned short, (_Float16)v);
  }
  if (idx < 64) {
    const float pA = pos_g[idx] * bninv;
    bnc[idx] = pA;
    bnc[64 + idx] = pA * pos_b[idx] + pos_bt[idx];
    const float aA = attn_g[idx] * bninv;
    bnc[128 + idx] = aA;
    bnc[192 + idx] = aA * attn_b[idx] + attn_bt[idx];
  }
}

// ---------------------------------------------------------------- kernel 1: v/k/q projections via 3-term f16 hi/lo MFMA
__global__ __launch_bounds__(256, 2) void proj_mfma(
    const float* __restrict__ x, const unsigned short* __restrict__ pj_img,
    const float* __restrict__ b0, const float* __restrict__ b1, const float* __restrict__ b2,
    float* __restrict__ o0, float* __restrict__ o1, float* __restrict__ o2) {
  __shared__ __align__(16) unsigned short s_xh[4096];
  __shared__ __align__(16) unsigned short s_xl[4096];
  __shared__ __align__(16) unsigned short s_w6[6 * 4096];
  const int tid = threadIdx.x;
  const int r0 = blockIdx.x << 6;
  for (int i = tid; i < 3072; i += 256)
    ((uint4*)s_w6)[i] = ((const uint4*)pj_img)[i];
  {
    const int row = tid >> 2, seg = tid & 3;
    const float* xr = x + (((size_t)(r0 + row)) << 6) + (seg << 4);
    float xb[16];
#pragma unroll
    for (int q = 0; q < 4; ++q) *(float4*)&xb[q * 4] = ((const float4*)xr)[q];
    h8 c0h, c1h, c0l, c1l;
#pragma unroll
    for (int e = 0; e < 8; ++e) {
      const _Float16 h0 = (_Float16)xb[e];
      c0h[e] = h0; c0l[e] = (_Float16)(xb[e] - (float)h0);
      const _Float16 h1 = (_Float16)xb[e + 8];
      c1h[e] = h1; c1l[e] = (_Float16)(xb[e + 8] - (float)h1);
    }
    const int base = row << 6;
    const int oi0 = base + ((((seg << 1) | 0) ^ (row & 7)) << 3);
    const int oi1 = base + ((((seg << 1) | 1) ^ (row & 7)) << 3);
    *(h8*)&s_xh[oi0] = c0h; *(h8*)&s_xh[oi1] = c1h;
    *(h8*)&s_xl[oi0] = c0l; *(h8*)&s_xl[oi1] = c1l;
  }
  __syncthreads();
  const int wv = tid >> 6, lane = tid & 63, lrow = lane >> 4, lcol = lane & 15;
  const int col = (wv << 4) + lcol;
  f32x4 acc[3][4];
#pragma unroll
  for (int o = 0; o < 3; ++o)
#pragma unroll
    for (int mt = 0; mt < 4; ++mt) acc[o][mt] = (f32x4){0.f, 0.f, 0.f, 0.f};
#pragma unroll
  for (int ks = 0; ks < 2; ++ks) {
    const int kc = lrow + (ks << 2);
    const int boff = (col << 6) + ((kc ^ (col & 7)) << 3);
    const h8 bh0 = *(const h8*)&s_w6[boff];
    const h8 bl0 = *(const h8*)&s_w6[4096 + boff];
    const h8 bh1 = *(const h8*)&s_w6[8192 + boff];
    const h8 bl1 = *(const h8*)&s_w6[12288 + boff];
    const h8 bh2 = *(const h8*)&s_w6[16384 + boff];
    const h8 bl2 = *(const h8*)&s_w6[20480 + boff];
#pragma unroll
    for (int mt = 0; mt < 4; ++mt) {
      const int m = (mt << 4) + lcol;
      const int aoff = (m << 6) + ((kc ^ (m & 7)) << 3);
      const h8 ah = *(const h8*)&s_xh[aoff];
      const h8 al = *(const h8*)&s_xl[aoff];
      acc[0][mt] = __builtin_amdgcn_mfma_f32_16x16x32_f16(ah, bh0, acc[0][mt], 0, 0, 0);
      acc[0][mt] = __builtin_amdgcn_mfma_f32_16x16x32_f16(al, bh0, acc[0][mt], 0, 0, 0);
      acc[0][mt] = __builtin_amdgcn_mfma_f32_16x16x32_f16(ah, bl0, acc[0][mt], 0, 0, 0);
      acc[1][mt] = __builtin_amdgcn_mfma_f32_16x16x32_f16(ah, bh1, acc[1][mt], 0, 0, 0);
      acc[1][mt] = __builtin_amdgcn_mfma_f32_16x16x32_f16(al, bh1, acc[1][mt], 0, 0, 0);
      acc[1][mt] = __builtin_amdgcn_mfma_f32_16x16x32_f16(ah, bl1, acc[1][mt], 0, 0, 0);
      acc[2][mt] = __builtin_amdgcn_mfma_f32_16x16x32_f16(ah, bh2, acc[2][mt], 0, 0, 0);
      acc[2][mt] = __builtin_amdgcn_mfma_f32_16x16x32_f16(al, bh2, acc[2][mt], 0, 0, 0);
      acc[2][mt] = __builtin_amdgcn_mfma_f32_16x16x32_f16(ah, bl2, acc[2][mt], 0, 0, 0);
    }
  }
  const float bb0 = b0[col], bb1 = b1[col], bb2 = b2[col];
#pragma unroll
  for (int mt = 0; mt < 4; ++mt)
#pragma unroll
    for (int r = 0; r < 4; ++r) {
      const size_t gi = (((size_t)(r0 + (mt << 4) + (lrow << 2) + r)) << 6) + col;
      o0[gi] = acc[0][mt][r] + bb0;
      o1[gi] = acc[1][mt][r] + bb1;
      o2[gi] = acc[2][mt][r] + bb2;
    }
}

// ---------------------------------------------------------------- kernel 2: exact radius-KNN (top-64 SET, index tiebreak)
// output word: low 31 bits = cloud-local neighbor index j, bit 31 = valid (d2 <= R^2)
__global__ __launch_bounds__(256) void knn_kernel(const float* __restrict__ pos,
                                                  unsigned* __restrict__ nbr) {
  __shared__ float spos[MM * 3];
  __shared__ unsigned long long slist[4][CAP];
  const int bidx = blockIdx.x;
  const int b = bidx >> 9;        // 512 blocks per cloud (4 queries each)
  const int qblk = bidx & 511;
  const int tid = threadIdx.x;
  const float* pc = pos + (size_t)b * MM * 3;
  for (int i = tid; i < MM * 3 / 4; i += 256)
    ((float4*)spos)[i] = ((const float4*)pc)[i];
  __syncthreads();
  const int wv = tid >> 6, lane = tid & 63;
  const int q = (qblk << 2) + wv;
  const float qx = spos[q * 3 + 0], qy = spos[q * 3 + 1], qz = spos[q * 3 + 2];
  unsigned bits[32];
  unsigned cnt = 0;
#pragma unroll
  for (int i = 0; i < 32; ++i) {
    const int j = lane + (i << 6);
    const float dx = qx - spos[j * 3 + 0];
    const float dy = qy - spos[j * 3 + 1];
    const float dz = qz - spos[j * 3 + 2];
    // match reference rounding exactly: ((dx*dx + dy*dy) + dz*dz), no fma contraction
    const float d2 = __fadd_rn(__fadd_rn(__fmul_rn(dx, dx), __fmul_rn(dy, dy)), __fmul_rn(dz, dz));
    const unsigned bt = __float_as_uint(d2);
    bits[i] = bt;
    const bool val = (d2 <= R2);
    const unsigned long long mb = __ballot(val);
    if (val) {
      const unsigned off = cnt + (unsigned)__popcll(mb & ((1ull << lane) - 1ull));
      if (off < CAP) slist[wv][off] = (((unsigned long long)bt) << 32) | (unsigned)j;
    }
    cnt += (unsigned)__popcll(mb);
  }
  __syncthreads();
  unsigned outv;
  if (cnt <= 64u) {
    if (lane < (int)cnt) outv = ((unsigned)slist[wv][lane]) | 0x80000000u;
    else                 outv = 0u;
  } else if (cnt <= (unsigned)CAP) {
    unsigned long long s0, s1, s2, s3, t;
    s0 = (lane       < (int)cnt) ? slist[wv][lane      ] : ~0ull;
    s1 = (lane + 64  < (int)cnt) ? slist[wv][lane + 64 ] : ~0ull;
    s2 = (lane + 128 < (int)cnt) ? slist[wv][lane + 128] : ~0ull;
    s3 = (lane + 192 < (int)cnt) ? slist[wv][lane + 192] : ~0ull;
    if (s1 < s0) { t = s0; s0 = s1; s1 = t; }
    if (s3 < s2) { t = s2; s2 = s3; s3 = t; }
    if (s2 < s0) { t = s0; s0 = s2; s2 = t; }
    if (s3 < s1) { t = s1; s1 = s3; s3 = t; }
    if (s2 < s1) { t = s1; s1 = s2; s2 = t; }
    if (cnt <= 128u) {
      // pop the (cnt-64) LARGEST; the 64 remaining are the answer set.
      const int pops = (int)cnt - 64;
      int rl = (cnt > (unsigned)lane) ? (int)((cnt - (unsigned)lane + 63u) >> 6) : 0;
      if (rl > 4) rl = 4;
      int ti = rl - 1;
      for (int p = 0; p < pops; ++p) {
        const unsigned long long mx =
            (ti == 3) ? s3 : (ti == 2) ? s2 : (ti == 1) ? s1 : (ti == 0) ? s0 : 0ull;
        const unsigned long long g = wave_max_u64(mx);
        if (ti >= 0 && mx == g) ti--;
      }
      const int c = ti + 1;
      const unsigned long long b0 = __ballot(c & 1);
      const unsigned long long b1 = __ballot(c & 2);
      const unsigned long long b2 = __ballot(c & 4);
      const unsigned long long lm = (1ull << lane) - 1ull;
      const int pre = __popcll(b0 & lm) + 2 * __popcll(b1 & lm) + 4 * __popcll(b2 & lm);
      if (c > 0) slist[wv][pre + 0] = s0;
      if (c > 1) slist[wv][pre + 1] = s1;
      if (c > 2) slist[wv][pre + 2] = s2;
      if (c > 3) slist[wv][pre + 3] = s3;
      __asm volatile("s_waitcnt lgkmcnt(0)" ::: "memory");
      outv = ((unsigned)slist[wv][lane]) | 0x80000000u;
    } else {
      unsigned long long my = 0;
      for (int it = 0; it < 64; ++it) {
        const unsigned long long gg = wave_min_u64(s0);
        if (lane == it) my = gg;
        if (s0 == gg) { s0 = s1; s1 = s2; s2 = s3; s3 = ~0ull; }
      }
      outv = ((unsigned)my) | 0x80000000u;
    }
  } else {
    unsigned long long cur = ~0ull;
#pragma unroll
    for (int i = 0; i < 32; ++i) {
      const unsigned long long k = (((unsigned long long)bits[i]) << 32) | (unsigned)(lane + (i << 6));
      cur = (k < cur) ? k : cur;
    }
    unsigned long long my = 0;
    for (int it = 0; it < 64; ++it) {
      const unsigned long long gg = wave_min_u64(cur);
      if (lane == it) my = gg;
      if (cur == gg) {
        cur = ~0ull;
#pragma unroll
        for (int i = 0; i < 32; ++i) {
          const unsigned long long k = (((unsigned long long)bits[i]) << 32) | (unsigned)(lane + (i << 6));
          if (k > gg && k < cur) cur = k;
        }
      }
    }
    const float d2s = __uint_as_float((unsigned)(my >> 32));
    outv = ((unsigned)my) | ((d2s <= R2) ? 0x80000000u : 0u);
  }
  nbr[((size_t)(b * MM + q)) * 64 + lane] = outv;
}

// ---------------------------------------------------------------- kernel 3: fused transformer conv
// one query per block; thread owns channel col = wv*16 + (lane&15), rows n = 16mt+4*(lane>>4)+r
// kf/vv neighbor rows staged to f16 LDS tiles; t built in place in the kf tile.
__global__ __launch_bounds__(256, 4) void ptc_kernel(
    const float* __restrict__ pos, const float* __restrict__ nrm,
    const float* __restrict__ vv, const float* __restrict__ kf, const float* __restrict__ qq,
    const unsigned* __restrict__ nbr,
    const unsigned short* __restrict__ w_img, const unsigned short* __restrict__ pw_img,
    const float* __restrict__ bnc,
    float* __restrict__ out) {
  __shared__ __align__(16) unsigned short s_w[4096];       // 8KB swizzled attn wT
  __shared__ __align__(16) unsigned short s_kt[4096];      // 8KB kf rows -> t (in place)
  __shared__ __align__(16) unsigned short s_vv[4096];      // 8KB vv rows
  __shared__ __align__(16) unsigned short s_pw[64 * 24];   // 3KB [col][k24]
  __shared__ __align__(16) unsigned short s_relh[64 * 24]; // 3KB [n][k24]
  __shared__ unsigned s_sel[64];
  const int qi = blockIdx.x;
  const int b = qi >> 11;
  const int tid = threadIdx.x;
  const int wv = tid >> 6, lane = tid & 63;
  const int lrow = lane >> 4, lcol = lane & 15;
  const int col = (wv << 4) + lcol;

  // ---- phase A: neighbor ids + weight-image staging
  if (tid < 64) s_sel[tid] = nbr[(size_t)qi * 64 + tid];
  {
    const uint4* wi = (const uint4*)w_img;
    uint4* sw = (uint4*)s_w;
    sw[tid] = wi[tid];
    sw[tid + 256] = wi[tid + 256];
    if (tid < 192) ((uint4*)s_pw)[tid] = ((const uint4*)pw_img)[tid];
  }
  __syncthreads();

  // ---- phase B: stage kf/vv neighbor rows (f16, swizzled); rel rows by tid<64
  {
    const int row = tid >> 2, seg = tid & 3;
    const int j = (int)(s_sel[row] & 0x7FFFFFFFu);
    const size_t rb = (((size_t)((b << 11) + j)) << 6) + (seg << 4);
    const float* kr = kf + rb;
    const float* vr = vv + rb;
    float kb[16], vb[16];
#pragma unroll
    for (int q = 0; q < 4; ++q) {
      *(float4*)&kb[q * 4] = ((const float4*)kr)[q];
      *(float4*)&vb[q * 4] = ((const float4*)vr)[q];
    }
    h8 kc0, kc1, vc0, vc1;
#pragma unroll
    for (int e = 0; e < 8; ++e) {
      kc0[e] = (_Float16)kb[e]; kc1[e] = (_Float16)kb[e + 8];
      vc0[e] = (_Float16)vb[e]; vc1[e] = (_Float16)vb[e + 8];
    }
    const int base = row << 6;
    const int oi0 = base + ((((seg << 1) | 0) ^ (row & 7)) << 3);
    const int oi1 = base + ((((seg << 1) | 1) ^ (row & 7)) << 3);
    *(h8*)&s_kt[oi0] = kc0; *(h8*)&s_kt[oi1] = kc1;
    *(h8*)&s_vv[oi0] = vc0; *(h8*)&s_vv[oi1] = vc1;
  }
  if (tid < 64) {
    const int j = (int)(s_sel[tid] & 0x7FFFFFFFu);
    const int jg = (b << 11) + j;
    h8 hv;
    hv[0] = (_Float16)(pos[(size_t)qi * 3 + 0] - pos[(size_t)jg * 3 + 0]);
    hv[1] = (_Float16)(pos[(size_t)qi * 3 + 1] - pos[(size_t)jg * 3 + 1]);
    hv[2] = (_Float16)(pos[(size_t)qi * 3 + 2] - pos[(size_t)jg * 3 + 2]);
    hv[3] = (_Float16)(nrm[(size_t)qi * 3 + 0] - nrm[(size_t)jg * 3 + 0]);
    hv[4] = (_Float16)(nrm[(size_t)qi * 3 + 1] - nrm[(size_t)jg * 3 + 1]);
    hv[5] = (_Float16)(nrm[(size_t)qi * 3 + 2] - nrm[(size_t)jg * 3 + 2]);
    hv[6] = (_Float16)0.f; hv[7] = (_Float16)0.f;
    *(h8*)&s_relh[tid * 24] = hv;
    h8 zz = (h8)(_Float16)0.f;
    *(h8*)&s_relh[tid * 24 + 8] = zz;
  }
  __syncthreads();

  // ---- delta-pre = rel @ pos_w via 4 MFMAs (K padded to 16)
  f32x4 dacc[4];
  {
    const h4 bpw = *(const h4*)&s_pw[col * 24 + (lrow << 2)];
#pragma unroll
    for (int mt = 0; mt < 4; ++mt) {
      const h4 ar = *(const h4*)&s_relh[((mt << 4) + lcol) * 24 + (lrow << 2)];
      dacc[mt] = __builtin_amdgcn_mfma_f32_16x16x16f16(ar, bpw, (f32x4){0.f, 0.f, 0.f, 0.f}, 0, 0, 0);
    }
  }

  // ---- t-build (in place): t = q - k + delta; delta kept in regs
  const float pA = bnc[col], pB = bnc[64 + col];
  const float aA = bnc[128 + col], aB = bnc[192 + col];
  const float qvc = qq[(size_t)qi * 64 + col];
  float def[16];
#pragma unroll
  for (int mt = 0; mt < 4; ++mt) {
#pragma unroll
    for (int r = 0; r < 4; ++r) {
      const int i = (mt << 2) + r;
      const int n = (mt << 4) + (lrow << 2) + r;
      const int hw = swz(n, col);
      const float kv = (float)*(const _Float16*)&s_kt[hw];
      const float de = fmaxf(fmaf(pA, dacc[mt][r], pB), 0.f);
      def[i] = de;
      const float t = qvc - kv + de;
      *(_Float16*)&s_kt[hw] = (_Float16)t;
    }
  }
  __syncthreads();

  // ---- alpha = t @ attn_w (f16 MFMA, wave owns 16 output cols)
  f32x4 acc[4];
#pragma unroll
  for (int mt = 0; mt < 4; ++mt) acc[mt] = (f32x4){0.f, 0.f, 0.f, 0.f};
#pragma unroll
  for (int ks = 0; ks < 2; ++ks) {
    const int kc = lrow + (ks << 2);
    const h8 bh = *(const h8*)&s_w[(col << 6) + ((kc ^ (col & 7)) << 3)];
#pragma unroll
    for (int mt = 0; mt < 4; ++mt) {
      const int m = (mt << 4) + lcol;
      const h8 ah = *(const h8*)&s_kt[(m << 6) + ((kc ^ (m & 7)) << 3)];
      acc[mt] = __builtin_amdgcn_mfma_f32_16x16x32_f16(ah, bh, acc[mt], 0, 0, 0);
    }
  }

  // ---- folded bn + relu + mask; per-channel softmax over 64 neighbors
  float a[16];
  float pm = -INFINITY;
#pragma unroll
  for (int mt = 0; mt < 4; ++mt) {
    const uint4 s4 = *(const uint4*)&s_sel[(mt << 4) + (lrow << 2)];
    const unsigned sv[4] = {s4.x, s4.y, s4.z, s4.w};
#pragma unroll
    for (int r = 0; r < 4; ++r) {
      const int i = (mt << 2) + r;
      const float al = fmaxf(fmaf(aA, acc[mt][r], aB), 0.f);
      const float av = (sv[r] >> 31) ? al : -INFINITY;
      a[i] = av;
      pm = fmaxf(pm, av);
    }
  }
  pm = fmaxf(pm, __shfl_xor(pm, 16, 64));
  pm = fmaxf(pm, __shfl_xor(pm, 32, 64));
  float ps = 0.f;
#pragma unroll
  for (int i = 0; i < 16; ++i) {
    const float e = __expf(a[i] - pm);   // masked -> exp(-inf) = 0
    a[i] = e;
    ps += e;
  }
  ps += __shfl_xor(ps, 16, 64);
  ps += __shfl_xor(ps, 32, 64);

  // ---- out[col] = (sum_n e_n * (v_n[col] + delta[n][col])) / sum_n e_n  (v from LDS)
  float o = 0.f;
#pragma unroll
  for (int mt = 0; mt < 4; ++mt) {
#pragma unroll
    for (int r = 0; r < 4; ++r) {
      const int i = (mt << 2) + r;
      const int n = (mt << 4) + (lrow << 2) + r;
      const float vj = (float)*(const _Float16*)&s_vv[swz(n, col)];
      o = fmaf(a[i], vj + def[i], o);
    }
  }
  o += __shfl_xor(o, 16, 64);
  o += __shfl_xor(o, 32, 64);
  if (lrow == 0) out[(size_t)qi * 64 + col] = o * (1.0f / ps);
}

// ---------------------------------------------------------------- launch
extern "C" void kernel_launch(void* const* d_in, const int* in_sizes, int n_in,
                              void* d_out, int out_size, void* d_ws, size_t ws_size,
                              hipStream_t stream) {
  const float* x      = (const float*)d_in[0];
  const float* pos    = (const float*)d_in[1];
  const float* nrm    = (const float*)d_in[2];
  const float* lin_w  = (const float*)d_in[4];
  const float* lin_b  = (const float*)d_in[5];
  const float* lsw    = (const float*)d_in[6];
  const float* lsb    = (const float*)d_in[7];
  const float* ldw    = (const float*)d_in[8];
  const float* ldb    = (const float*)d_in[9];
  const float* pos_w  = (const float*)d_in[10];
  const float* pos_b  = (const float*)d_in[11];
  const float* pos_g  = (const float*)d_in[12];
  const float* pos_bt = (const float*)d_in[13];
  const float* attn_w = (const float*)d_in[14];
  const float* attn_b = (const float*)d_in[15];
  const float* attn_g = (const float*)d_in[16];
  const float* attn_bt= (const float*)d_in[17];
  float* out = (float*)d_out;

  float* wsf = (float*)d_ws;
  float* v   = wsf;
  float* kf  = wsf + (size_t)NTOT * 64;
  float* qv  = wsf + (size_t)2 * NTOT * 64;
  unsigned* nbr = (unsigned*)(wsf + (size_t)3 * NTOT * 64);
  unsigned short* w_img  = (unsigned short*)(wsf + (size_t)4 * NTOT * 64);
  unsigned short* pw_img = w_img + 4096;
  unsigned short* pj_img = pw_img + 1536;
  float* bnc = (float*)(pj_img + 24576);

  prep_w<<<16, 256, 0, stream>>>(attn_w, pos_w, lin_w, lsw, ldw,
                                 pos_b, pos_g, pos_bt, attn_b, attn_g, attn_bt,
                                 w_img, pw_img, pj_img, bnc);
  proj_mfma<<<NTOT / 64, 256, 0, stream>>>(
      x, pj_img, lin_b, lsb, ldb, v, kf, qv);
  knn_kernel<<<BB * (MM / 4), 256, 0, stream>>>(pos, nbr);
  ptc_kernel<<<NTOT, 256, 0, stream>>>(
      pos, nrm, v, kf, qv, nbr, w_img, pw_img, bnc, out);
}